// Round 3
// baseline (165.342 us; speedup 1.0000x reference)
//
#include <hip/hip_runtime.h>
#include <hip/hip_bf16.h>

// ILA layer (all fp32): key = W@ft, query = W@fk (1x1 conv, shared W),
// sim[p,k] = <query[p], key[neighbor_k(p)]> over 9x9 window (zero-padded keys),
// weight = softmax_k(sim)  (OOB entries participate with sim=0),
// out[c,p] = sum_k weight[k] * ft[c, neighbor_k(p)]  (zero-padded ft).
// n=2, c=128, h=w=64, L=9 (81 neighbors).

#define Hh 64
#define Ww 64
#define Cc 128
#define Nn 2
#define KK 81
#define HW (Hh * Ww)          // 4096
#define CHW (Cc * HW)         // 524288
#define P_TOT (Nn * HW)       // 8192

__device__ __forceinline__ void fma4(float4& a, const float4 b, const float s) {
    a.x += b.x * s; a.y += b.y * s; a.z += b.z * s; a.w += b.w * s;
}

// ---------------- Kernel A: projection (K = W*ft, Q = W*fk), pixel-major fp32 out.
// 256 blocks x 256 threads; 32 pixels/block; thread tile = 4 pixels x 4 outputs.
// W staged in 4 i-chunks [32][132]; x tiles staged transposed [i][pixel] with pad 36.
__global__ __launch_bounds__(256) void proj_kernel(const float* __restrict__ ft,
                                                   const float* __restrict__ fk,
                                                   const float* __restrict__ Wm,
                                                   float* __restrict__ Qbuf,
                                                   float* __restrict__ Kbuf) {
    __shared__ __align__(16) float Wl[32 * 132];    // [ii][o], chunked over i
    __shared__ __align__(16) float xkl[128 * 36];   // [i][p_local]
    __shared__ __align__(16) float xql[128 * 36];
    const int t = threadIdx.x;
    const int p0 = blockIdx.x * 32;        // 4096 % 32 == 0: block never crosses n
    const int nn = p0 >> 12;
    const int sp0 = p0 & 4095;
    const int gbase = nn * CHW + sp0;

    // stage x tiles: 128 ch x 32 pixels, coalesced 32-float segments per channel
    for (int idx = t; idx < 128 * 32; idx += 256) {
        const int c = idx >> 5, pl = idx & 31;
        xkl[c * 36 + pl] = ft[gbase + c * HW + pl];
        xql[c * 36 + pl] = fk[gbase + c * HW + pl];
    }

    const int po = t & 7;                  // pixel group: 8 groups x 4 pixels
    const int oo = t >> 3;                 // output group: 32 groups x 4 outputs
    float4 accK[4], accQ[4];
#pragma unroll
    for (int i = 0; i < 4; ++i) { accK[i] = make_float4(0,0,0,0); accQ[i] = make_float4(0,0,0,0); }

    for (int ch = 0; ch < 4; ++ch) {
        // stage W chunk transposed: Wl[ii][o] <- Wm[o][ch*32+ii]
        for (int idx = t; idx < 128 * 32; idx += 256) {
            const int o = idx >> 5, ii = idx & 31;
            Wl[ii * 132 + o] = Wm[o * 128 + (ch << 5) + ii];
        }
        __syncthreads();
#pragma unroll 8
        for (int ii = 0; ii < 32; ++ii) {
            const int i = (ch << 5) + ii;
            const float4 w4 = *(const float4*)&Wl[ii * 132 + (oo << 2)];
            const float4 k4 = *(const float4*)&xkl[i * 36 + (po << 2)];
            const float4 q4 = *(const float4*)&xql[i * 36 + (po << 2)];
            fma4(accK[0], w4, k4.x); fma4(accK[1], w4, k4.y);
            fma4(accK[2], w4, k4.z); fma4(accK[3], w4, k4.w);
            fma4(accQ[0], w4, q4.x); fma4(accQ[1], w4, q4.y);
            fma4(accQ[2], w4, q4.z); fma4(accQ[3], w4, q4.w);
        }
        __syncthreads();
    }

#pragma unroll
    for (int pp = 0; pp < 4; ++pp) {
        const int p = p0 + (po << 2) + pp;
        *(float4*)&Kbuf[p * 128 + (oo << 2)] = accK[pp];
        *(float4*)&Qbuf[p * 128 + (oo << 2)] = accQ[pp];
    }
}

// ---------------- Kernel B: sim + softmax, one block (128 thr) per pixel.
// OOB neighbors have sim = 0 (zero-padded keys) and DO participate in softmax.
__global__ __launch_bounds__(128) void sim_softmax_kernel(const float* __restrict__ Qbuf,
                                                          const float* __restrict__ Kbuf,
                                                          float* __restrict__ wT) {
    __shared__ __align__(16) float qv[128];
    __shared__ float simb[KK];
    const int t = threadIdx.x;
    const int p = blockIdx.x;
    const int nn = p >> 12;
    const int sp = p & 4095;
    const int y = sp >> 6, x = sp & 63;

    qv[t] = Qbuf[p * 128 + t];
    __syncthreads();

    if (t < KK) {
        const int dy = t / 9 - 4, dx = t % 9 - 4;
        const int yy = y + dy, xx = x + dx;
        float a = 0.f;
        if ((unsigned)yy < 64u && (unsigned)xx < 64u) {
            const float4* kp = (const float4*)(Kbuf + (size_t)((nn << 12) + (yy << 6) + xx) * 128);
            const float4* qp = (const float4*)qv;
#pragma unroll 8
            for (int ci = 0; ci < 32; ++ci) {
                const float4 kv = kp[ci];
                const float4 qq = qp[ci];
                a += qq.x * kv.x + qq.y * kv.y + qq.z * kv.z + qq.w * kv.w;
            }
        }
        simb[t] = a;
    }
    __syncthreads();

    if (t < 64) {
        const float v0 = simb[t];
        const float v1 = (t + 64 < KK) ? simb[t + 64] : -1e30f;
        float m = fmaxf(v0, v1);
#pragma unroll
        for (int off = 32; off; off >>= 1) m = fmaxf(m, __shfl_xor(m, off));
        const float e0 = __expf(v0 - m);
        const float e1 = (t + 64 < KK) ? __expf(v1 - m) : 0.f;
        float s = e0 + e1;
#pragma unroll
        for (int off = 32; off; off >>= 1) s += __shfl_xor(s, off);
        const float inv = 1.f / s;
        wT[t * P_TOT + p] = e0 * inv;                       // transposed: [k][p]
        if (t + 64 < KK) wT[(t + 64) * P_TOT + p] = e1 * inv;
    }
}

// ---------------- Kernel C: out[c,p] = sum_k w[k,p] * ft[c, neighbor_k(p)]
// block = 256 threads, handles (n, row y, 16-channel group); row's weights staged in LDS.
__global__ __launch_bounds__(256) void weight_kernel(const float* __restrict__ ft,
                                                     const float* __restrict__ wT,
                                                     float* __restrict__ out) {
    __shared__ float wl[KK * 64];   // [k][x] for this row
    const int t = threadIdx.x;
    const int b = blockIdx.x;       // ((nn*64 + y)*8 + cg)
    const int cg = b & 7;
    const int y  = (b >> 3) & 63;
    const int nn = b >> 9;
    const int rowbase = (nn << 12) + (y << 6);

    for (int idx = t; idx < KK * 64; idx += 256) {
        const int k = idx >> 6, x = idx & 63;
        wl[idx] = wT[k * P_TOT + rowbase + x];   // coalesced per k
    }
    __syncthreads();

    const int wave = t >> 6, x = t & 63;
#pragma unroll
    for (int ci = 0; ci < 4; ++ci) {
        const int c = (cg << 4) + (wave << 2) + ci;
        const float* fbase = ft + (size_t)(nn * Cc + c) * HW;
        float acc = 0.f;
#pragma unroll
        for (int k = 0; k < KK; ++k) {
            const int dy = k / 9 - 4, dx = k % 9 - 4;
            const int yy = y + dy;          // uniform across lanes
            const int xx = x + dx;          // per-lane
            if ((unsigned)yy < 64u && (unsigned)xx < 64u)
                acc += wl[(k << 6) + x] * fbase[(yy << 6) + xx];
        }
        out[(size_t)(nn * Cc + c) * HW + (y << 6) + x] = acc;
    }
}

extern "C" void kernel_launch(void* const* d_in, const int* in_sizes, int n_in,
                              void* d_out, int out_size, void* d_ws, size_t ws_size,
                              hipStream_t stream) {
    const float* ft = (const float*)d_in[0];
    const float* fk = (const float*)d_in[1];
    const float* Wm = (const float*)d_in[2];
    float* out = (float*)d_out;

    float* ws   = (float*)d_ws;          // ~10.7 MB: Q(4MB) + K(4MB) + wT(2.66MB)
    float* Qbuf = ws;                    // [p][c]  8192*128
    float* Kbuf = ws + 1048576;          // [p][c]  8192*128
    float* wT   = ws + 2097152;          // [k][p]  81*8192

    proj_kernel<<<256, 256, 0, stream>>>(ft, fk, Wm, Qbuf, Kbuf);
    sim_softmax_kernel<<<P_TOT, 128, 0, stream>>>(Qbuf, Kbuf, wT);
    weight_kernel<<<1024, 256, 0, stream>>>(ft, wT, out);
}

// Round 4
// 143.973 us; speedup vs baseline: 1.1484x; 1.1484x over previous
//
#include <hip/hip_runtime.h>
#include <hip/hip_bf16.h>

// ILA layer (all fp32): key = W@ft, query = W@fk (1x1 conv, shared W),
// sim[p,k] = <query[p], key[neighbor_k(p)]> over 9x9 window (zero-padded keys),
// weight = softmax_k(sim)  (OOB entries participate with sim=0),
// out[c,p] = sum_k weight[k] * ft[c, neighbor_k(p)]  (zero-padded ft).
// n=2, c=128, h=w=64, L=9 (81 neighbors).

#define Hh 64
#define Ww 64
#define Cc 128
#define Nn 2
#define KK 81
#define HW (Hh * Ww)          // 4096
#define CHW (Cc * HW)         // 524288
#define P_TOT (Nn * HW)       // 8192

__device__ __forceinline__ void fma4(float4& a, const float4 b, const float s) {
    a.x += b.x * s; a.y += b.y * s; a.z += b.z * s; a.w += b.w * s;
}

// ---------------- Kernel A: projection (K = W*ft, Q = W*fk), pixel-major fp32 out.
// 512 blocks x 256 thr; 16 px/block; thread = 4 px x 2 out x {K,Q}.
__global__ __launch_bounds__(256) void proj_kernel(const float* __restrict__ ft,
                                                   const float* __restrict__ fk,
                                                   const float* __restrict__ Wm,
                                                   float* __restrict__ Qbuf,
                                                   float* __restrict__ Kbuf) {
    __shared__ __align__(16) float Wl[32 * 132];   // [ii][o] chunk of W^T
    __shared__ __align__(16) float xkl[128 * 20];  // [i][pl], pad 20
    __shared__ __align__(16) float xql[128 * 20];
    const int t = threadIdx.x;
    const int p0 = blockIdx.x * 16;       // 4096 % 16 == 0: never crosses n
    const int nn = p0 >> 12;
    const int gbase = nn * CHW + (p0 & 4095);

    for (int e = t; e < 128 * 16; e += 256) {       // stage x tiles (coalesced 64B runs)
        const int c = e >> 4, pl = e & 15;
        xkl[c * 20 + pl] = ft[gbase + c * HW + pl];
        xql[c * 20 + pl] = fk[gbase + c * HW + pl];
    }

    const int po = t & 3;                 // 4 pixel groups x 4 px
    const int oo = t >> 2;                // 64 out groups x 2 out
    float4 aK0 = make_float4(0,0,0,0), aK1 = aK0, aQ0 = aK0, aQ1 = aK0;

    for (int ch = 0; ch < 4; ++ch) {
        for (int e = t; e < 128 * 32; e += 256) {   // Wl[ii][o] <- Wm[o][ch*32+ii]
            const int o = e >> 5, ii = e & 31;
            Wl[ii * 132 + o] = Wm[o * 128 + (ch << 5) + ii];
        }
        __syncthreads();
#pragma unroll 8
        for (int ii = 0; ii < 32; ++ii) {
            const float2 w2 = *(const float2*)&Wl[ii * 132 + (oo << 1)];  // contiguous: conflict-free
            const float4 k4 = *(const float4*)&xkl[((ch << 5) + ii) * 20 + (po << 2)];
            const float4 q4 = *(const float4*)&xql[((ch << 5) + ii) * 20 + (po << 2)];
            fma4(aK0, k4, w2.x); fma4(aK1, k4, w2.y);
            fma4(aQ0, q4, w2.x); fma4(aQ1, q4, w2.y);
        }
        __syncthreads();
    }

    const float kx[4] = {aK0.x, aK0.y, aK0.z, aK0.w};
    const float ky[4] = {aK1.x, aK1.y, aK1.z, aK1.w};
    const float qx[4] = {aQ0.x, aQ0.y, aQ0.z, aQ0.w};
    const float qy[4] = {aQ1.x, aQ1.y, aQ1.z, aQ1.w};
#pragma unroll
    for (int pp = 0; pp < 4; ++pp) {
        const size_t base = (size_t)(p0 + (po << 2) + pp) * 128 + (oo << 1);
        *(float2*)&Kbuf[base] = make_float2(kx[pp], ky[pp]);
        *(float2*)&Qbuf[base] = make_float2(qx[pp], qy[pp]);
    }
}

// ---------------- Kernel B: sim + softmax. Block = 8-pixel row strip.
// K neighborhood (9 rows x 16 cols = 144 vectors) + Q staged in LDS with
// XOR-swizzled float4 chunks: slot(v,ci) = v*32 + (ci ^ (v&31)) -> bank-floor reads.
__global__ __launch_bounds__(256) void sim_softmax_kernel(const float* __restrict__ Qbuf,
                                                          const float* __restrict__ Kbuf,
                                                          float* __restrict__ wT) {
    __shared__ __align__(16) float lds[20104];  // Ksw 18432 | Qsw 1024 | simb 648
    float* Ksw  = lds;
    float* Qsw  = lds + 18432;
    float* simb = lds + 19456;
    float* red  = lds + 18432;                  // aliases Qsw after dots are done

    const int t  = threadIdx.x;
    const int b  = blockIdx.x;
    const int x0 = (b & 7) << 3;
    const int y  = (b >> 3) & 63;
    const int nn = b >> 9;
    const int pg0 = (nn << 12) + (y << 6) + x0;

    // stage K: zero-padded window, coalesced 512B runs per vector
    for (int e = t; e < 144 * 32; e += 256) {
        const int v = e >> 5, ci = e & 31;
        const int gx = x0 + (v & 15) - 4;
        const int gy = y + (v >> 4) - 4;
        float4 val = make_float4(0, 0, 0, 0);
        if ((unsigned)gx < 64u && (unsigned)gy < 64u)
            val = *(const float4*)&Kbuf[(size_t)((nn << 12) + (gy << 6) + gx) * 128 + (ci << 2)];
        *(float4*)&Ksw[(v << 7) + (((ci ^ (v & 31)) << 2))] = val;
    }
    {   // stage Q: 8 vectors, 256 threads = exactly 8*32 chunks
        const int v = t >> 5, ci = t & 31;
        const float4 val = *(const float4*)&Qbuf[(size_t)(pg0 + v) * 128 + (ci << 2)];
        *(float4*)&Qsw[(v << 7) + ((ci ^ v) << 2)] = val;
    }
    __syncthreads();

    // dots: thread -> (pixel p, k in {kb, kb+32, kb+64})
    const int p = t & 7, kb = t >> 3;
    const bool has2 = (kb + 64 < KK);
    const int k0 = kb, k1 = kb + 32, k2 = has2 ? kb + 64 : kb;
    const int v0 = (k0 / 9) * 16 + p + k0 % 9;
    const int v1 = (k1 / 9) * 16 + p + k1 % 9;
    const int v2 = (k2 / 9) * 16 + p + k2 % 9;
    const int b0 = v0 << 7, m0 = v0 & 31;
    const int b1 = v1 << 7, m1 = v1 & 31;
    const int b2 = v2 << 7, m2 = v2 & 31;
    const int bq = p << 7;
    float4 a0 = make_float4(0,0,0,0), a1 = a0, a2 = a0;
#pragma unroll
    for (int ci = 0; ci < 32; ++ci) {
        const float4 q4 = *(const float4*)&Qsw[bq + ((ci ^ p) << 2)];
        const float4 kA = *(const float4*)&Ksw[b0 + ((ci ^ m0) << 2)];
        const float4 kB = *(const float4*)&Ksw[b1 + ((ci ^ m1) << 2)];
        const float4 kC = *(const float4*)&Ksw[b2 + ((ci ^ m2) << 2)];
        a0.x += q4.x*kA.x; a0.y += q4.y*kA.y; a0.z += q4.z*kA.z; a0.w += q4.w*kA.w;
        a1.x += q4.x*kB.x; a1.y += q4.y*kB.y; a1.z += q4.z*kB.z; a1.w += q4.w*kB.w;
        a2.x += q4.x*kC.x; a2.y += q4.y*kC.y; a2.z += q4.z*kC.z; a2.w += q4.w*kC.w;
    }
    __syncthreads();          // Qsw dead after this; `red` may now use its space
    simb[k0 * 8 + p] = a0.x + a0.y + a0.z + a0.w;
    simb[k1 * 8 + p] = a1.x + a1.y + a1.z + a1.w;
    if (has2) simb[(kb + 64) * 8 + p] = a2.x + a2.y + a2.z + a2.w;
    __syncthreads();

    // softmax over 81 (OOB k's have sim = 0 from zero-padded K — matches reference)
    if (t < 128) {            // phase 1: partial max, 16 j-slices x 8 px
        const int j = t >> 3, pp = t & 7;
        float m = -1e30f;
        for (int k = j; k < KK; k += 16) m = fmaxf(m, simb[k * 8 + pp]);
        red[j * 8 + pp] = m;
    }
    __syncthreads();
    if (t < 8) {
        float m = red[t];
        for (int j = 1; j < 16; ++j) m = fmaxf(m, red[j * 8 + t]);
        red[128 + t] = m;
    }
    __syncthreads();
    if (t < 128) {            // phase 2: exp in-place + partial sums
        const int j = t >> 3, pp = t & 7;
        const float mm = red[128 + pp];
        float s = 0.f;
        for (int k = j; k < KK; k += 16) {
            const float e = __expf(simb[k * 8 + pp] - mm);
            simb[k * 8 + pp] = e;
            s += e;
        }
        red[j * 8 + pp] = s;  // overwrites phase-1 partials (safe: mfin at 128+)
    }
    __syncthreads();
    if (t < 8) {
        float s = red[t];
        for (int j = 1; j < 16; ++j) s += red[j * 8 + t];
        red[136 + t] = 1.f / s;
    }
    __syncthreads();

    const float inv = red[136 + p];
    wT[k0 * P_TOT + pg0 + p] = simb[k0 * 8 + p] * inv;
    wT[k1 * P_TOT + pg0 + p] = simb[k1 * 8 + p] * inv;
    if (has2) wT[(kb + 64) * P_TOT + pg0 + p] = simb[(kb + 64) * 8 + p] * inv;
}

// ---------------- Kernel C: out[c,p] = sum_k w[k,p] * ft[c, neighbor_k(p)]
// Block = (n, row y, 16-ch group). ft staged channel-interleaved [row][xx][c], pad 20:
// k-loop reads are lane-contiguous b128 at the bank floor; zero-padding staged -> no branches.
__global__ __launch_bounds__(256) void weight_kernel(const float* __restrict__ ft,
                                                     const float* __restrict__ wT,
                                                     float* __restrict__ out) {
    __shared__ float wl[KK * 64];                    // 20.7 KB
    __shared__ __align__(16) float ftl[9 * 72 * 20]; // 51.8 KB
    const int t = threadIdx.x;
    const int b = blockIdx.x;
    const int cg = b & 7;
    const int y  = (b >> 3) & 63;
    const int nn = b >> 9;
    const int rowbase = (nn << 12) + (y << 6);

    for (int e = t; e < KK * 64; e += 256)
        wl[e] = wT[(e >> 6) * P_TOT + rowbase + (e & 63)];

    for (int e = t; e < 9 * 72 * 16; e += 256) {
        const int xx = e % 72;
        const int rc = e / 72;
        const int r = rc % 9, c = rc / 9;
        const int gx = xx - 4, gy = y + r - 4;
        float v = 0.f;
        if ((unsigned)gx < 64u && (unsigned)gy < 64u)
            v = ft[(size_t)(((nn * Cc + (cg << 4) + c) << 12) + (gy << 6) + gx)];
        ftl[(r * 72 + xx) * 20 + c] = v;
    }
    __syncthreads();

    const int x = t & 63, q = t >> 6;               // q: 4-channel quad
    float4 acc = make_float4(0, 0, 0, 0);
#pragma unroll
    for (int k = 0; k < KK; ++k) {
        const int r = k / 9, dx = k % 9;
        const float4 f4 = *(const float4*)&ftl[(r * 72 + x + dx) * 20 + (q << 2)];
        const float w = wl[(k << 6) + x];
        fma4(acc, f4, w);
    }
    const size_t ob = (size_t)(((nn * Cc + (cg << 4) + (q << 2)) << 12) + (y << 6) + x);
    out[ob]             = acc.x;
    out[ob + HW]        = acc.y;
    out[ob + 2 * HW]    = acc.z;
    out[ob + 3 * HW]    = acc.w;
}

extern "C" void kernel_launch(void* const* d_in, const int* in_sizes, int n_in,
                              void* d_out, int out_size, void* d_ws, size_t ws_size,
                              hipStream_t stream) {
    const float* ft = (const float*)d_in[0];
    const float* fk = (const float*)d_in[1];
    const float* Wm = (const float*)d_in[2];
    float* out = (float*)d_out;

    float* ws   = (float*)d_ws;          // ~10.7 MB: Q(4MB) + K(4MB) + wT(2.66MB)
    float* Qbuf = ws;                    // [p][c]  8192*128
    float* Kbuf = ws + 1048576;          // [p][c]  8192*128
    float* wT   = ws + 2097152;          // [k][p]  81*8192

    proj_kernel<<<512, 256, 0, stream>>>(ft, fk, Wm, Qbuf, Kbuf);
    sim_softmax_kernel<<<1024, 256, 0, stream>>>(Qbuf, Kbuf, wT);
    weight_kernel<<<1024, 256, 0, stream>>>(ft, wT, out);
}